// Round 1
// baseline (648.148 us; speedup 1.0000x reference)
//
#include <hip/hip_runtime.h>
#include <hip/hip_fp16.h>

typedef _Float16 f16;
typedef _Float16 f16x8 __attribute__((ext_vector_type(8)));
typedef float f32x4 __attribute__((ext_vector_type(4)));

#define BATCH 8
#define C_IN 512
#define C_OUT 512
#define HH 64
#define WW 64
#define WDIM 512
#define HW (HH*WW)

// ---------------- kernel 1: style s = Linear(w)*c_lin + bias ----------------
__global__ void style_kernel(const float* __restrict__ w,
                             const float* __restrict__ lin_w,
                             const float* __restrict__ lin_b,
                             float* __restrict__ s) {
    __shared__ float wl[WDIM];
    int b = blockIdx.x;
    int t = threadIdx.x;
    wl[t]       = w[b * WDIM + t];
    wl[t + 256] = w[b * WDIM + t + 256];
    __syncthreads();
    const float c_lin = 0.04419417382415922f;  // 1/sqrt(512)
    for (int rep = 0; rep < 2; ++rep) {
        int c = t + rep * 256;
        const float4* lw = (const float4*)(lin_w + (size_t)c * WDIM);
        float acc = 0.f;
        #pragma unroll 4
        for (int d4 = 0; d4 < WDIM / 4; ++d4) {
            float4 v = lw[d4];
            acc += v.x * wl[d4*4+0] + v.y * wl[d4*4+1]
                 + v.z * wl[d4*4+2] + v.w * wl[d4*4+3];
        }
        s[b * C_IN + c] = acc * c_lin + lin_b[c];
    }
}

// ------- kernel 2: modulate+demodulate -> f16 weights [b][o][tap][i] -------
__global__ void modw_kernel(const float* __restrict__ cw,
                            const float* __restrict__ s,
                            f16* __restrict__ wmod) {
    int b = blockIdx.x & 7;
    int o = blockIdx.x >> 3;
    int t = threadIdx.x;
    const float c_conv = 0.014731391274719739f;  // 1/sqrt(512*9)
    float svals[2];
    float cwv[2][9];
    float part = 0.f;
    #pragma unroll
    for (int r = 0; r < 2; ++r) {
        int i = t + r * 256;
        float si = s[b * C_IN + i] * c_conv;
        svals[r] = si;
        const float* base = cw + ((size_t)o * C_IN + i) * 9;
        float sq = 0.f;
        #pragma unroll
        for (int k = 0; k < 9; ++k) { float v = base[k]; cwv[r][k] = v; sq += v * v; }
        part += sq * si * si;
    }
    // block reduction (256 threads = 4 waves)
    #pragma unroll
    for (int m = 1; m < 64; m <<= 1) part += __shfl_xor(part, m, 64);
    __shared__ float red[4];
    if ((t & 63) == 0) red[t >> 6] = part;
    __syncthreads();
    float total = red[0] + red[1] + red[2] + red[3];
    float sinv = rsqrtf(total + 1e-8f);
    size_t obase = ((size_t)(b * C_OUT + o)) * 9 * C_IN;
    #pragma unroll
    for (int r = 0; r < 2; ++r) {
        int i = t + r * 256;
        float scale = svals[r] * sinv;
        #pragma unroll
        for (int k = 0; k < 9; ++k) {
            wmod[obase + (size_t)k * C_IN + i] = (f16)(cwv[r][k] * scale);
        }
    }
}

// ---------------- kernel 3: grouped conv as implicit GEMM (MFMA f16) -------
// Block: BM=128 o  x  BN=128 pixels (2 image rows). 4 waves (2 M x 2 N).
// K loop: 16 chunks of 32 input channels; inner loop over 9 taps.
// LDS x tile: [4 rows][66 cols][32 ch] f16, row stride padded to 40 f16 (80B)
// so consecutive-pixel lanes step 20 banks (near conflict-free b128 access).
#define ICH 32
#define ICP 40   // padded channel stride in LDS
__global__ void conv_kernel(const float* __restrict__ x,
                            const f16* __restrict__ wmod,
                            float* __restrict__ y) {
    __shared__ f16 xs[4 * 66 * ICP];  // 21120 B

    int tid  = threadIdx.x;
    int blk  = blockIdx.x;
    int b    = blk >> 7;
    int rem  = blk & 127;
    int mt   = rem >> 5;   // 0..3   (o tile of 128)
    int nt   = rem & 31;   // 0..31  (pixel tile of 128 = 2 rows)
    int wave = tid >> 6, lane = tid & 63;
    int wm = wave >> 1, wn = wave & 1;
    int l15 = lane & 15, l4 = lane >> 4;
    int h0 = nt * 2;

    f32x4 acc[4][4] = {};

    const float* xb = x + (size_t)b * C_IN * HW;
    const f16*   wb = wmod + ((size_t)(b * C_OUT + mt * 128 + wm * 64)) * (9 * C_IN);

    // zero the always-zero halo columns (w = -1 and w = 64)
    if (tid < 32) {
        int r = tid >> 3, side = (tid >> 2) & 1, io = tid & 3;
        f16x8 z = {};
        *(f16x8*)&xs[(r * 66 + (side ? 65 : 0)) * ICP + io * 8] = z;
    }

    // staging role of this thread: one (row, col), 4 channel-octets per chunk
    int sc = tid & 63;          // col 0..63
    int sr = tid >> 6;          // row 0..3
    int hr = h0 - 1 + sr;       // input image row (may be out of range)
    bool rowok = (hr >= 0) && (hr < HH);
    const float* xrow = xb + (size_t)hr * WW + sc;

    for (int ic = 0; ic < C_IN / ICH; ++ic) {
        __syncthreads();   // previous compute done (also covers halo init)
        #pragma unroll
        for (int io = 0; io < 4; ++io) {
            float v[8];
            #pragma unroll
            for (int j = 0; j < 8; ++j) {
                int i = ic * ICH + io * 8 + j;
                v[j] = rowok ? xrow[(size_t)i * HW] : 0.f;
            }
            f16x8 h;
            #pragma unroll
            for (int j = 0; j < 8; ++j) h[j] = (f16)v[j];
            *(f16x8*)&xs[(sr * 66 + sc + 1) * ICP + io * 8] = h;
        }
        __syncthreads();

        #pragma unroll
        for (int t = 0; t < 9; ++t) {
            const int dy = t / 3, dx = t % 3;
            f16x8 af[4];
            #pragma unroll
            for (int mf = 0; mf < 4; ++mf) {
                const f16* ap = wb + (size_t)(mf * 16 + l15) * (9 * C_IN)
                              + t * C_IN + ic * ICH + l4 * 8;
                af[mf] = *(const f16x8*)ap;
            }
            f16x8 bf[4];
            #pragma unroll
            for (int nf = 0; nf < 4; ++nf) {
                int pl = wn * 64 + nf * 16 + l15;    // 0..127 within tile
                int rp = pl >> 6, wc = pl & 63;
                bf[nf] = *(const f16x8*)&xs[((rp + dy) * 66 + wc + dx) * ICP + l4 * 8];
            }
            #pragma unroll
            for (int mf = 0; mf < 4; ++mf)
                #pragma unroll
                for (int nf = 0; nf < 4; ++nf)
                    acc[mf][nf] = __builtin_amdgcn_mfma_f32_16x16x32_f16(
                        af[mf], bf[nf], acc[mf][nf], 0, 0, 0);
        }
    }

    // epilogue: D lane mapping col(=pixel)=lane&15, row(=o)=(lane>>4)*4+q
    float* yb = y + ((size_t)(b * C_OUT + mt * 128 + wm * 64)) * HW + h0 * WW;
    #pragma unroll
    for (int mf = 0; mf < 4; ++mf) {
        #pragma unroll
        for (int q = 0; q < 4; ++q) {
            int o = mf * 16 + l4 * 4 + q;
            #pragma unroll
            for (int nf = 0; nf < 4; ++nf) {
                int pl = wn * 64 + nf * 16 + l15;
                yb[(size_t)o * HW + pl] = acc[mf][nf][q];
            }
        }
    }
}

extern "C" void kernel_launch(void* const* d_in, const int* in_sizes, int n_in,
                              void* d_out, int out_size, void* d_ws, size_t ws_size,
                              hipStream_t stream) {
    const float* x   = (const float*)d_in[0];   // [8,512,64,64]
    const float* w   = (const float*)d_in[1];   // [8,512]
    const float* cw  = (const float*)d_in[2];   // [512,512,3,3]
    const float* lw  = (const float*)d_in[3];   // [512,512]
    const float* lb  = (const float*)d_in[4];   // [512]
    float* y = (float*)d_out;

    float* s    = (float*)d_ws;                      // 16 KB
    f16*   wmod = (f16*)((char*)d_ws + 16 * 1024);   // 37.75 MB, [b][o][tap][i]

    style_kernel<<<8, 256, 0, stream>>>(w, lw, lb, s);
    modw_kernel<<<BATCH * C_OUT, 256, 0, stream>>>(cw, s, wmod);
    conv_kernel<<<1024, 256, 0, stream>>>(x, wmod, y);
}

// Round 4
// 342.302 us; speedup vs baseline: 1.8935x; 1.8935x over previous
//
#include <hip/hip_runtime.h>
#include <hip/hip_fp16.h>

typedef _Float16 f16;
typedef _Float16 f16x8 __attribute__((ext_vector_type(8)));
typedef float f32x4 __attribute__((ext_vector_type(4)));

#define BATCH 8
#define C_IN 512
#define C_OUT 512
#define HH 64
#define WW 64
#define WDIM 512
#define HW (HH*WW)

// workspace layout (bytes)
#define WS_S_OFF     0           // style s: 8*512*4 = 16384
#define WS_ZERO_OFF  16384       // zero page: 4096
#define WS_WMOD_OFF  20480       // wmod f16: 8*512*9*512*2 = 37748736
#define WS_XT_OFF    37769216    // xT f16:   8*4096*512*2  = 33554432  (end ~71.3MB)

__device__ __forceinline__ void gld_lds16(const void* g, void* l) {
    __builtin_amdgcn_global_load_lds(
        (const __attribute__((address_space(1))) void*)g,
        (__attribute__((address_space(3))) void*)l, 16, 0, 0);
}

// ---------------- kernel 1: style s = Linear(w)*c_lin + bias ----------------
__global__ void style_kernel(const float* __restrict__ w,
                             const float* __restrict__ lin_w,
                             const float* __restrict__ lin_b,
                             float* __restrict__ s) {
    __shared__ float wl[WDIM];
    int b = blockIdx.x;
    int t = threadIdx.x;
    wl[t]       = w[b * WDIM + t];
    wl[t + 256] = w[b * WDIM + t + 256];
    __syncthreads();
    const float c_lin = 0.04419417382415922f;  // 1/sqrt(512)
    for (int rep = 0; rep < 2; ++rep) {
        int c = t + rep * 256;
        const float4* lw = (const float4*)(lin_w + (size_t)c * WDIM);
        float acc = 0.f;
        #pragma unroll 4
        for (int d4 = 0; d4 < WDIM / 4; ++d4) {
            float4 v = lw[d4];
            acc += v.x * wl[d4*4+0] + v.y * wl[d4*4+1]
                 + v.z * wl[d4*4+2] + v.w * wl[d4*4+3];
        }
        s[b * C_IN + c] = acc * c_lin + lin_b[c];
    }
}

// ------- kernel 2: modulate+demodulate -> f16 weights [b][o][tap][i] -------
__global__ void modw_kernel(const float* __restrict__ cw,
                            const float* __restrict__ s,
                            f16* __restrict__ wmod) {
    int b = blockIdx.x & 7;
    int o = blockIdx.x >> 3;
    int t = threadIdx.x;
    const float c_conv = 0.014731391274719739f;  // 1/sqrt(512*9)
    float svals[2];
    float cwv[2][9];
    float part = 0.f;
    #pragma unroll
    for (int r = 0; r < 2; ++r) {
        int i = t + r * 256;
        float si = s[b * C_IN + i] * c_conv;
        svals[r] = si;
        const float* base = cw + ((size_t)o * C_IN + i) * 9;
        float sq = 0.f;
        #pragma unroll
        for (int k = 0; k < 9; ++k) { float v = base[k]; cwv[r][k] = v; sq += v * v; }
        part += sq * si * si;
    }
    #pragma unroll
    for (int m = 1; m < 64; m <<= 1) part += __shfl_xor(part, m, 64);
    __shared__ float red[4];
    if ((t & 63) == 0) red[t >> 6] = part;
    __syncthreads();
    float total = red[0] + red[1] + red[2] + red[3];
    float sinv = rsqrtf(total + 1e-8f);
    size_t obase = ((size_t)(b * C_OUT + o)) * 9 * C_IN;
    #pragma unroll
    for (int r = 0; r < 2; ++r) {
        int i = t + r * 256;
        float scale = svals[r] * sinv;
        #pragma unroll
        for (int k = 0; k < 9; ++k) {
            wmod[obase + (size_t)k * C_IN + i] = (f16)(cwv[r][k] * scale);
        }
    }
}

// -------- kernel 3: transpose+convert x[b][c][h][w] f32 -> xT[b][h][w][c] f16
__global__ void xpose_kernel(const float* __restrict__ x, f16* __restrict__ xT) {
    __shared__ float tl[128 * 68];   // [ch_local][w] pad 68 (16B-aligned rows)
    int bid = blockIdx.x;
    int cb  = bid & 3;          // channel block of 128
    int h   = (bid >> 2) & 63;
    int b   = bid >> 8;
    int tid = threadIdx.x;
    const float* xb = x + ((size_t)(b * C_IN + cb * 128)) * HW + h * WW;
    int w4  = (tid & 15) * 4;
    int chl = tid >> 4;
    #pragma unroll
    for (int k = 0; k < 8; ++k) {
        int ch = chl + k * 16;
        float4 v = *(const float4*)(xb + (size_t)ch * HW + w4);
        *(float4*)&tl[ch * 68 + w4] = v;
    }
    __syncthreads();
    int w = tid >> 2, part = tid & 3;
    f16* dst = xT + ((size_t)b * HW + h * WW + w) * C_IN + cb * 128 + part * 32;
    #pragma unroll
    for (int jo = 0; jo < 4; ++jo) {
        f16x8 hv;
        #pragma unroll
        for (int e = 0; e < 8; ++e) hv[e] = (f16)tl[(part * 32 + jo * 8 + e) * 68 + w];
        *(f16x8*)(dst + jo * 8) = hv;
    }
}

// ---------------- kernel 4: conv as m97-style implicit GEMM ----------------
// BM=128 o, BN=128 pix (2 rows), BKC=32 ch/chunk, 9 taps inner, 16 chunks.
// 4 waves (2M x 2N), per step: 4 af + 4 bf ds_read_b128 + 16 MFMA, 1 barrier.
// LDS: xbuf[2] 17408B each (1088 segs: 4 rows * 264 + 32 pad), wbuf[2] 8192B.
// Swizzle (both tiles): phys_seg = g ^ ((g>>3)&3)  -> conflict-free b128 reads
// (per ds_read quarter: each of the 8 four-bank groups hit by exactly 2 lanes).
#define XBYTES 17408
#define WOFF   (2*XBYTES)          // 34816
#define LDSSZ  (2*XBYTES + 2*8192) // 51200

__global__ __launch_bounds__(256, 3)
void conv_kernel(const f16* __restrict__ xT, const f16* __restrict__ wmod,
                 const f16* __restrict__ zbuf, float* __restrict__ y) {
    __shared__ char lds[LDSSZ];
    char* ldsp = (char*)lds;

    const int tid = threadIdx.x;
    int bid0 = blockIdx.x;
    int wg = (bid0 & 7) * 128 + (bid0 >> 3);   // XCD-contiguous (1024%8==0)
    const int b  = wg >> 7;
    const int mt = (wg >> 5) & 3;
    const int nt = wg & 31;
    const int wave = tid >> 6, lane = tid & 63;
    const int wm = wave >> 1, wn = wave & 1;
    const int l15 = lane & 15, l4 = lane >> 4;
    const int h0 = nt * 2;

    // ---- weight staging sources (2 segs/thread) ----
    const f16* wb_base = wmod + (size_t)(b * C_OUT + mt * 128) * 9 * C_IN;
    int wp0 = tid, wp1 = tid + 256;
    int wg0 = wp0 ^ ((wp0 >> 3) & 3), wg1 = wp1 ^ ((wp1 >> 3) & 3);
    const f16* wsrc0 = wb_base + (size_t)(wg0 >> 2) * (9 * C_IN) + (wg0 & 3) * 8;
    const f16* wsrc1 = wb_base + (size_t)(wg1 >> 2) * (9 * C_IN) + (wg1 & 3) * 8;

    // ---- x staging sources (5 rounds; halo/OOB -> zero page) ----
    const f16* xTb = xT + (size_t)b * HW * C_IN;
    const f16 *xsA, *xsB, *xsC, *xsD, *xsE;
#define XDECODE(P, DST) { int p = (P); int row = p / 264; int q = p - row * 264; \
    int g = q ^ ((q >> 3) & 3); int wc = g >> 2; int oct = g & 3; \
    int hr = h0 - 1 + row; int col = wc - 1; \
    bool v = (p < 1056) && (hr >= 0) && (hr < HH) && (col >= 0) && (col < WW); \
    DST = v ? (xTb + (size_t)(hr * WW + col) * C_IN + oct * 8) : zbuf; }
    XDECODE(tid,        xsA)
    XDECODE(tid + 256,  xsB)
    XDECODE(tid + 512,  xsC)
    XDECODE(tid + 768,  xsD)
    XDECODE(1024 + (tid & 63), xsE)
#undef XDECODE

    // ---- af LDS byte offsets (within wbuf) ----
    // Includes the wave's M-offset wm*64 (R2->R3 fix).
    int afoff[4];
    #pragma unroll
    for (int mf = 0; mf < 4; ++mf) {
        int g = (wm * 64 + mf * 16 + l15) * 4 + l4;
        int ph = g ^ ((g >> 3) & 3);
        afoff[mf] = WOFF + ph * 16;
    }
    // ---- bf pixel decode ----
    int wcb[4], rpb[4];
    #pragma unroll
    for (int nf = 0; nf < 4; ++nf) {
        int pl = wn * 64 + nf * 16 + l15;
        rpb[nf] = pl >> 6;
        wcb[nf] = pl & 63;
    }

    f32x4 acc[4][4] = {};

    auto STAGE_W = [&](int dsel, int off) {  // off in f16 units: t*512 + ic*32
        char* d0 = ldsp + WOFF + dsel * 8192 + wave * 1024;
        gld_lds16(wsrc0 + off, d0);
        gld_lds16(wsrc1 + off, d0 + 4096);
    };
    auto STAGE_X = [&](int dsel) {
        char* base = ldsp + dsel * XBYTES + wave * 1024;
        gld_lds16(xsA, base);
        gld_lds16(xsB, base + 4096);
        gld_lds16(xsC, base + 8192);
        gld_lds16(xsD, base + 12288);
        if (tid < 64) gld_lds16(xsE, ldsp + dsel * XBYTES + 16384);
        xsA += 32; xsB += 32; xsC += 32; xsD += 32; xsE += 32;
    };

    // prologue
    STAGE_W(0, 0);
    STAGE_X(0);
    __syncthreads();

    for (int ic = 0; ic < 16; ++ic) {
        const int xsel = ic & 1;
        #pragma unroll
        for (int t = 0; t < 9; ++t) {
            const int wsel = (ic + t) & 1;
            // prefetch next step's weights / next chunk's x
            if (!(t == 8 && ic == 15)) {
                int tn  = (t == 8) ? 0 : t + 1;
                int icn = (t == 8) ? ic + 1 : ic;
                STAGE_W(wsel ^ 1, tn * C_IN + icn * 32);
            }
            if (t == 0 && ic < 15) STAGE_X(xsel ^ 1);

            const int dy = t / 3, dx = t % 3;   // compile-time (t unrolled)
            f16x8 af[4], bf[4];
            #pragma unroll
            for (int mf = 0; mf < 4; ++mf)
                af[mf] = *(const f16x8*)(ldsp + wsel * 8192 + afoff[mf]);
            #pragma unroll
            for (int nf = 0; nf < 4; ++nf) {
                int q  = (wcb[nf] + dx) * 4 + l4;
                int ph = q ^ ((q >> 3) & 3);
                bf[nf] = *(const f16x8*)(ldsp + xsel * XBYTES
                                         + (rpb[nf] + dy) * 4224 + ph * 16);
            }
            #pragma unroll
            for (int mf = 0; mf < 4; ++mf)
                #pragma unroll
                for (int nf = 0; nf < 4; ++nf)
                    acc[mf][nf] = __builtin_amdgcn_mfma_f32_16x16x32_f16(
                        af[mf], bf[nf], acc[mf][nf], 0, 0, 0);
            __syncthreads();
        }
    }

    // epilogue: D mapping col(=pixel)=lane&15, row(=o)=(lane>>4)*4+q
    float* yb = y + ((size_t)(b * C_OUT + mt * 128 + wm * 64)) * HW + h0 * WW;
    #pragma unroll
    for (int mf = 0; mf < 4; ++mf) {
        #pragma unroll
        for (int q = 0; q < 4; ++q) {
            int o = mf * 16 + l4 * 4 + q;
            #pragma unroll
            for (int nf = 0; nf < 4; ++nf) {
                int pl = wn * 64 + nf * 16 + l15;
                yb[(size_t)o * HW + pl] = acc[mf][nf][q];
            }
        }
    }
}

extern "C" void kernel_launch(void* const* d_in, const int* in_sizes, int n_in,
                              void* d_out, int out_size, void* d_ws, size_t ws_size,
                              hipStream_t stream) {
    const float* x   = (const float*)d_in[0];   // [8,512,64,64]
    const float* w   = (const float*)d_in[1];   // [8,512]
    const float* cw  = (const float*)d_in[2];   // [512,512,3,3]
    const float* lw  = (const float*)d_in[3];   // [512,512]
    const float* lb  = (const float*)d_in[4];   // [512]
    float* y = (float*)d_out;

    float* s    = (float*)((char*)d_ws + WS_S_OFF);
    f16*   zb   = (f16*)((char*)d_ws + WS_ZERO_OFF);
    f16*   wmod = (f16*)((char*)d_ws + WS_WMOD_OFF);
    f16*   xT   = (f16*)((char*)d_ws + WS_XT_OFF);

    hipMemsetAsync((char*)d_ws + WS_ZERO_OFF, 0, 4096, stream);
    style_kernel<<<8, 256, 0, stream>>>(w, lw, lb, s);
    modw_kernel<<<BATCH * C_OUT, 256, 0, stream>>>(cw, s, wmod);
    xpose_kernel<<<2048, 256, 0, stream>>>(x, xT);
    conv_kernel<<<1024, 256, 0, stream>>>(xT, wmod, zb, y);
}